// Round 5
// baseline (602.438 us; speedup 1.0000x reference)
//
#include <hip/hip_runtime.h>

#define IN_C 128
#define HEADS 4
#define OUT_C 64
#define OUT_F 256   // HEADS*OUT_C
#define NEG_SLOPE 0.2f
#define BN_EPS 1e-5f
#define SP_BLOCKS 1024
#define MT 64       // gemm M-tile

typedef __attribute__((ext_vector_type(8))) short short8;
typedef __attribute__((ext_vector_type(4))) float floatx4;

__device__ __forceinline__ unsigned short f2bf(float f) {
    unsigned u = __float_as_uint(f);
    u += 0x7FFF + ((u >> 16) & 1);   // round-to-nearest-even
    return (unsigned short)(u >> 16);
}
__device__ __forceinline__ float bf2f(unsigned short u) {
    return __uint_as_float(((unsigned)u) << 16);
}

// ---------------- Wp prep: fragment-ordered bf16 weights ----------------
// Wp[((w*4+kt)*4+nt)*512 + l*8 + j] = bf16( W[(kt*32+(l>>4)*8+j) * OUT_F + (w*64+nt*16+(l&15))] )
__global__ void wtprep_kernel(const float* __restrict__ W, unsigned short* __restrict__ Wp)
{
    int idx = blockIdx.x * blockDim.x + threadIdx.x;   // 0..32767
    int j  = idx & 7;
    int l  = (idx >> 3) & 63;
    int nt = (idx >> 9) & 3;
    int kt = (idx >> 11) & 3;
    int w  = idx >> 13;
    int k   = kt * 32 + (l >> 4) * 8 + j;
    int col = w * 64 + nt * 16 + (l & 15);
    Wp[idx] = f2bf(W[(size_t)k * OUT_F + col]);
}

// ---------------- MFMA GEMM: h(bf16) = x @ W, + per-head attention dots ----------------
// M-tile = 64 nodes/block; wave w == head w; 256 MFMAs per block.
// LDS union: As (64x136 bf16, 17.4KB) during K-loop, then Hs (64x264 bf16, 33.8KB).
__global__ __launch_bounds__(256) void gemm_mfma_kernel(
    const float* __restrict__ x, const unsigned short* __restrict__ Wp,
    const float* __restrict__ att_src, const float* __restrict__ att_dst,
    unsigned short* __restrict__ h, float* __restrict__ a_src, float* __restrict__ a_dst,
    int n)
{
    __shared__ unsigned short sh[MT * 264];   // 33.8 KB (union of As / Hs)

    const int t = threadIdx.x;
    const int w = t >> 6;          // wave == head
    const int l = t & 63;
    const int quad = l >> 4;
    const int c15 = l & 15;
    const int base = blockIdx.x * MT;
    const bool full = (base + MT <= n);

    // ---- stage A: 64 rows x 128 k, fp32 -> bf16 LDS (row stride 136 shorts) ----
#pragma unroll
    for (int i = 0; i < 8; ++i) {
        int idx = t + i * 256;          // float4 index 0..2047 (32 per row)
        int row = idx >> 5;
        int k = (idx & 31) * 4;
        float4 v;
        if (full || base + row < n) v = *(const float4*)(x + (size_t)(base + row) * IN_C + k);
        else v = make_float4(0.f, 0.f, 0.f, 0.f);
        ushort4 b;
        b.x = f2bf(v.x); b.y = f2bf(v.y); b.z = f2bf(v.z); b.w = f2bf(v.w);
        *(ushort4*)&sh[row * 136 + k] = b;
    }
    __syncthreads();

    // ---- K loop: 4 ksteps x 4 m-subtiles x 4 n-subtiles ----
    floatx4 acc[4][4] = {};
#pragma unroll
    for (int kt = 0; kt < 4; ++kt) {
        short8 bfrag[4];
#pragma unroll
        for (int nt = 0; nt < 4; ++nt)
            bfrag[nt] = *(const short8*)(Wp + (((w * 4 + kt) * 4 + nt) << 9) + l * 8);
        int k0 = kt * 32 + quad * 8;
#pragma unroll
        for (int m = 0; m < 4; ++m) {
            short8 afrag = *(const short8*)&sh[(m * 16 + c15) * 136 + k0];
#pragma unroll
            for (int nt = 0; nt < 4; ++nt)
                acc[m][nt] = __builtin_amdgcn_mfma_f32_16x16x32_bf16(afrag, bfrag[nt], acc[m][nt], 0, 0, 0);
        }
    }

    __syncthreads();   // all A reads done before Hs overwrites the union

    // ---- epilogue: attention dots + Hs staging (row stride 264 shorts) ----
    float asum[4][4] = {}, adsum[4][4] = {};
#pragma unroll
    for (int nt = 0; nt < 4; ++nt) {
        int col = w * 64 + nt * 16 + c15;
        float aw = att_src[col];
        float dw = att_dst[col];
#pragma unroll
        for (int m = 0; m < 4; ++m)
#pragma unroll
            for (int r = 0; r < 4; ++r) {
                float v = acc[m][nt][r];
                sh[(m * 16 + quad * 4 + r) * 264 + col] = f2bf(v);
                asum[m][r] = fmaf(v, aw, asum[m][r]);
                adsum[m][r] = fmaf(v, dw, adsum[m][r]);
            }
    }
#pragma unroll
    for (int m = 0; m < 4; ++m)
#pragma unroll
        for (int r = 0; r < 4; ++r) {
            float vs = asum[m][r], vd = adsum[m][r];
#pragma unroll
            for (int mm = 1; mm < 16; mm <<= 1) {
                vs += __shfl_xor(vs, mm, 64);
                vd += __shfl_xor(vd, mm, 64);
            }
            if (c15 == 0) {
                int node = base + m * 16 + quad * 4 + r;
                if (full || node < n) {
                    a_src[(size_t)node * HEADS + w] = vs;
                    a_dst[(size_t)node * HEADS + w] = vd;
                }
            }
        }

    __syncthreads();
    // ---- coalesced h write: 64x256 bf16 ----
#pragma unroll
    for (int i = 0; i < 8; ++i) {
        int chunk = t + i * 256;        // int4 (8 shorts) index; 32 per row
        int row = chunk >> 5;
        int c0 = (chunk & 31) * 8;
        if (full || base + row < n) {
            int4 v = *(const int4*)&sh[row * 264 + c0];
            *(int4*)(h + (size_t)(base + row) * OUT_F + c0) = v;
        }
    }
}

// ---------------- CSR build ----------------
__global__ void deg_kernel(const int* __restrict__ ei, int* __restrict__ deg, int E)
{
    int e = blockIdx.x * blockDim.x + threadIdx.x;
    if (e < E) atomicAdd(&deg[ei[E + e]], 1);
}

__global__ void offsets_kernel(const int* __restrict__ deg, int* __restrict__ offsets,
                               int* __restrict__ cursor, int* __restrict__ gcursor, int n)
{
    int i = blockIdx.x * blockDim.x + threadIdx.x;
    int lane = threadIdx.x & 63;
    int cnt = (i < n) ? deg[i] : 0;
    int incl = cnt;
#pragma unroll
    for (int o = 1; o < 64; o <<= 1) {
        int v = __shfl_up(incl, o, 64);
        if (lane >= o) incl += v;
    }
    int total = __shfl(incl, 63, 64);
    int base = 0;
    if (lane == 63) base = atomicAdd(gcursor, total);
    base = __shfl(base, 63, 64);
    int off = base + incl - cnt;
    if (i < n) { offsets[i] = off; cursor[i] = off; }
}

__global__ void scatter_kernel(const int* __restrict__ ei, int* __restrict__ cursor,
                               int* __restrict__ srcs, int E)
{
    int e = blockIdx.x * blockDim.x + threadIdx.x;
    if (e < E) {
        int dst = ei[E + e];
        int pos = atomicAdd(&cursor[dst], 1);
        srcs[pos] = ei[e];
    }
}

// ---------------- Aggregation: one wave per dst, 8x-unrolled (no stats fusion) ----------------
__global__ __launch_bounds__(256) void agg_kernel(
    const unsigned short* __restrict__ h, const float* __restrict__ a_src,
    const float* __restrict__ a_dst, const int* __restrict__ offsets,
    const int* __restrict__ deg, const int* __restrict__ srcs,
    const float* __restrict__ bias, float* __restrict__ out, int n)
{
    int wave = (blockIdx.x * blockDim.x + threadIdx.x) >> 6;
    int lane = threadIdx.x & 63;
    int dst = wave;
    if (dst >= n) return;
    int myh = lane >> 4;

    float adh = a_dst[(size_t)dst * HEADS + myh];

    // self loop
    float es = a_src[(size_t)dst * HEADS + myh] + adh;
    es = (es > 0.f) ? es : NEG_SLOPE * es;
    float wgt = __expf(es);
    ushort4 hv = ((const ushort4*)(h + (size_t)dst * OUT_F))[lane];
    float4 acc;
    acc.x = bf2f(hv.x) * wgt; acc.y = bf2f(hv.y) * wgt;
    acc.z = bf2f(hv.z) * wgt; acc.w = bf2f(hv.w) * wgt;
    float wsum = wgt;

    const int start = offsets[dst];
    const int cnt = deg[dst];
    int j = 0;
    for (; j + 8 <= cnt; j += 8) {
        int s[8];
#pragma unroll
        for (int u = 0; u < 8; ++u) s[u] = srcs[start + j + u];
        float ew[8];
#pragma unroll
        for (int u = 0; u < 8; ++u) ew[u] = a_src[(size_t)s[u] * HEADS + myh];
        ushort4 hh[8];
#pragma unroll
        for (int u = 0; u < 8; ++u) hh[u] = ((const ushort4*)(h + (size_t)s[u] * OUT_F))[lane];
#pragma unroll
        for (int u = 0; u < 8; ++u) {
            float e = ew[u] + adh;
            e = (e > 0.f) ? e : NEG_SLOPE * e;
            float wv = __expf(e);
            acc.x = fmaf(bf2f(hh[u].x), wv, acc.x);
            acc.y = fmaf(bf2f(hh[u].y), wv, acc.y);
            acc.z = fmaf(bf2f(hh[u].z), wv, acc.z);
            acc.w = fmaf(bf2f(hh[u].w), wv, acc.w);
            wsum += wv;
        }
    }
    for (; j < cnt; ++j) {
        int s = srcs[start + j];
        float e = a_src[(size_t)s * HEADS + myh] + adh;
        e = (e > 0.f) ? e : NEG_SLOPE * e;
        float we = __expf(e);
        ushort4 hs = ((const ushort4*)(h + (size_t)s * OUT_F))[lane];
        acc.x = fmaf(bf2f(hs.x), we, acc.x);
        acc.y = fmaf(bf2f(hs.y), we, acc.y);
        acc.z = fmaf(bf2f(hs.z), we, acc.z);
        acc.w = fmaf(bf2f(hs.w), we, acc.w);
        wsum += we;
    }

    float inv = 1.f / (wsum + 1e-16f);
    float4 b4 = ((const float4*)bias)[lane];
    float4 o4;
    o4.x = fmaf(acc.x, inv, b4.x);
    o4.y = fmaf(acc.y, inv, b4.y);
    o4.z = fmaf(acc.z, inv, b4.z);
    o4.w = fmaf(acc.w, inv, b4.w);
    ((float4*)(out + (size_t)dst * OUT_F))[lane] = o4;
}

// ---------------- BatchNorm stats (two-level) + apply + ELU ----------------
__global__ __launch_bounds__(256) void stats_partial_kernel(const float* __restrict__ out,
                                                            float* __restrict__ partial, int n)
{
    int c = threadIdx.x;
    int b = blockIdx.x;
    float s = 0.f, s2 = 0.f;
    for (int r = b; r < n; r += SP_BLOCKS) {
        float v = out[(size_t)r * OUT_F + c];
        s += v;
        s2 = fmaf(v, v, s2);
    }
    partial[(size_t)c * SP_BLOCKS + b] = s;
    partial[(size_t)(c + OUT_F) * SP_BLOCKS + b] = s2;
}

// one block per column c: reduce partials for s and s2, emit scale/shift
__global__ void statsfinal_kernel(const float* __restrict__ partial,
                                  const float* __restrict__ gamma,
                                  const float* __restrict__ beta,
                                  float* __restrict__ ss, int n)
{
    int c = blockIdx.x;    // 0..255
    int l = threadIdx.x;   // 0..63
    float s = 0.f, s2 = 0.f;
    for (int j = l; j < SP_BLOCKS; j += 64) {
        s  += partial[(size_t)c * SP_BLOCKS + j];
        s2 += partial[(size_t)(c + OUT_F) * SP_BLOCKS + j];
    }
#pragma unroll
    for (int m = 32; m > 0; m >>= 1) {
        s  += __shfl_down(s, m, 64);
        s2 += __shfl_down(s2, m, 64);
    }
    if (l == 0) {
        float invn = 1.f / (float)n;
        float mean = s * invn;
        float var = s2 * invn - mean * mean;
        float sc = gamma[c] * rsqrtf(var + BN_EPS);
        ss[c] = sc;
        ss[OUT_F + c] = beta[c] - mean * sc;
    }
}

__device__ __forceinline__ float elu1(float v) {
    return (v > 0.f) ? v : expm1f(v);
}

__global__ __launch_bounds__(256) void bn_elu_kernel(float* __restrict__ out,
                                                     const float* __restrict__ ss,
                                                     long long n4)
{
    long long idx = (long long)blockIdx.x * blockDim.x + threadIdx.x;
    if (idx >= n4) return;
    int col4 = (int)(idx & 63);
    float4 v = ((float4*)out)[idx];
    float4 sc = ((const float4*)ss)[col4];
    float4 sh = ((const float4*)(ss + OUT_F))[col4];
    v.x = elu1(fmaf(v.x, sc.x, sh.x));
    v.y = elu1(fmaf(v.y, sc.y, sh.y));
    v.z = elu1(fmaf(v.z, sc.z, sh.z));
    v.w = elu1(fmaf(v.w, sc.w, sh.w));
    ((float4*)out)[idx] = v;
}

// ---------------- launch ----------------
extern "C" void kernel_launch(void* const* d_in, const int* in_sizes, int n_in,
                              void* d_out, int out_size, void* d_ws, size_t ws_size,
                              hipStream_t stream)
{
    const float* x       = (const float*)d_in[0];
    const int*   ei      = (const int*)d_in[1];
    const float* W       = (const float*)d_in[2];
    const float* att_src = (const float*)d_in[3];
    const float* att_dst = (const float*)d_in[4];
    const float* bias    = (const float*)d_in[5];
    const float* gamma   = (const float*)d_in[6];
    const float* beta    = (const float*)d_in[7];
    float* out = (float*)d_out;

    const int n = in_sizes[0] / IN_C;      // 100000
    const int E = in_sizes[1] / 2;         // 1600000

    float* ws = (float*)d_ws;
    size_t o = 0;
    unsigned short* h  = (unsigned short*)(ws + o); o += (size_t)n * OUT_F / 2;  // bf16
    unsigned short* Wp = (unsigned short*)(ws + o); o += IN_C * OUT_F / 2;       // bf16, frag-packed
    float* a_src  = ws + o; o += (size_t)n * HEADS;
    float* a_dst  = ws + o; o += (size_t)n * HEADS;
    float* ss     = ws + o; o += 2 * OUT_F;
    float* partial = ws + o; o += (size_t)2 * OUT_F * SP_BLOCKS;
    int* offsets  = (int*)(ws + o); o += n;
    int* cursor   = (int*)(ws + o); o += n;
    int* srcs     = (int*)(ws + o); o += E;
    // zero-initialized region (contiguous): deg, gcursor
    int* deg      = (int*)(ws + o); o += n;
    int* gcursor  = (int*)(ws + o); o += 1;

    hipMemsetAsync(deg, 0, ((size_t)n + 1) * sizeof(int), stream);

    wtprep_kernel<<<(IN_C * OUT_F) / 256, 256, 0, stream>>>(W, Wp);
    gemm_mfma_kernel<<<(n + MT - 1) / MT, 256, 0, stream>>>(x, Wp, att_src, att_dst, h, a_src, a_dst, n);
    deg_kernel<<<(E + 255) / 256, 256, 0, stream>>>(ei, deg, E);
    offsets_kernel<<<(n + 255) / 256, 256, 0, stream>>>(deg, offsets, cursor, gcursor, n);
    scatter_kernel<<<(E + 255) / 256, 256, 0, stream>>>(ei, cursor, srcs, E);
    agg_kernel<<<(n + 3) / 4, 256, 0, stream>>>(h, a_src, a_dst, offsets, deg, srcs, bias, out, n);
    stats_partial_kernel<<<SP_BLOCKS, 256, 0, stream>>>(out, partial, n);
    statsfinal_kernel<<<2 * OUT_F / 2, 64, 0, stream>>>(partial, gamma, beta, ss, n);
    bn_elu_kernel<<<(int)(((long long)n * 64 + 255) / 256), 256, 0, stream>>>(out, ss, (long long)n * 64);
}